// Round 21
// baseline (131.482 us; speedup 1.0000x reference)
//
#include <hip/hip_runtime.h>
#include <hip/hip_fp16.h>
#include <math.h>

// Problem constants: E=1,000,000  R=1000  D=200  N_BATCH=50,000  N_TOTAL=100,000
#define DD     200
#define DD3    600
#define NBK    256     // radix buckets = chunk(r>>5, 32) * 8 + g(slot>>13, 8)
#define GB     256     // sort grid blocks (one per CU)
#define SCH    8192    // blocksort entries per chunk (4096 edges)
#define SCAP   11264   // sortbucket LDS capacity (uint16)
#define CHUNK  1024    // partial8 slot-staging chunk
#define KP     232     // padded K (bf16): 464B row stride (16B-aligned b128 reads)
#define MP     2048    // padded M (rs rows)
#define NP     640     // padded N (gate cols)

typedef unsigned int   uint32;
typedef unsigned short uint16;
typedef __attribute__((ext_vector_type(8))) short bf16x8;
typedef __attribute__((ext_vector_type(4))) float f32x4;

static __device__ inline float bf2f(uint16 u) {
    union { uint32 i; float f; } x; x.i = ((uint32)u) << 16; return x.f;
}
static __device__ inline uint16 f2bf(float f) {
    union { float f; uint32 i; } x; x.f = f;
    return (uint16)((x.i + 0x7FFFu + ((x.i >> 16) & 1u)) >> 16);
}
static __device__ inline float asf(uint32 u) {
    union { uint32 i; float f; } x; x.i = u; return x.f;
}
static __device__ inline uint32 packbf(float a, float b) {
    return (uint32)f2bf(a) | ((uint32)f2bf(b) << 16);
}
static __device__ inline uint32 packh2(float a, float b) {
    __half2 h = __floats2half2_rn(a, b);
    union { __half2 h; uint32 u; } x; x.h = h; return x.u;
}
static __device__ inline __half2 ash2(uint32 u) {
    union { uint32 u; __half2 h; } x; x.u = u; return x.h;
}

// ---------------- zero int counters ----------------
__global__ void zero_kernel(int* __restrict__ cnt, int n) {
    int stride = gridDim.x * blockDim.x;
    for (int i = blockIdx.x * blockDim.x + threadIdx.x; i < n; i += stride) cnt[i] = 0;
}

// ---------------- zero float buffer ----------------
__global__ void zerof_kernel(float* __restrict__ p, int n) {
    int stride = gridDim.x * blockDim.x;
    for (int i = blockIdx.x * blockDim.x + threadIdx.x; i < n; i += stride) p[i] = 0.f;
}

// ---- fused pass A: blocks 0..GB-1 histogram -> boff[blk][bin];
//      blocks GB..  compact rows to fp16 (independent work, overlapped) ----
__launch_bounds__(512)
__global__ void hist_compact_kernel(const int* __restrict__ etype, const int* __restrict__ eidx,
                                    int* __restrict__ boff, int E,
                                    const int* __restrict__ node_id, const float* __restrict__ emb,
                                    uint32* __restrict__ cmp, int NB) {
    const int tid = threadIdx.x;
    if (blockIdx.x < GB) {
        __shared__ int lc[NBK];
        if (tid < NBK) lc[tid] = 0;
        __syncthreads();
        int per = (E + GB - 1) / GB;
        int beg = blockIdx.x * per;
        int end = min(E, beg + per);
        for (int e = beg + tid; e < end; e += 512) {
            int r  = etype[e];
            int ch = r >> 5;
            atomicAdd(&lc[(ch << 3) | (eidx[e] >> 13)], 1);
            atomicAdd(&lc[(ch << 3) | (eidx[E + e] >> 13)], 1);
        }
        __syncthreads();
        if (tid < NBK) boff[blockIdx.x * NBK + tid] = lc[tid];
    } else {
        int idx = (blockIdx.x - GB) * 512 + tid;
        int stride = (gridDim.x - GB) * 512;
        int total = NB * 50;
        for (; idx < total; idx += stride) {
            int s = idx / 50, q = idx - s * 50;
            int nid = node_id[s];
            float4 v = *(const float4*)(emb + (size_t)nid * DD + 4 * q);
            *(uint2*)(cmp + (size_t)s * 100 + 2 * q) = make_uint2(packh2(v.x, v.y), packh2(v.z, v.w));
        }
    }
}

// ---- offscanA: per-bin parallel scan over GB block-counts (grid NBK, GB thr) ----
__launch_bounds__(GB)
__global__ void offscanA_kernel(int* __restrict__ boff, int* __restrict__ tot) {
    __shared__ int s[GB];
    const int g   = blockIdx.x;       // bin
    const int tid = threadIdx.x;      // block index
    int v = boff[(size_t)tid * NBK + g];
    s[tid] = v;
    for (int off = 1; off < GB; off <<= 1) {
        __syncthreads();
        int t2 = (tid >= off) ? s[tid - off] : 0;
        __syncthreads();
        s[tid] += t2;
    }
    __syncthreads();
    boff[(size_t)tid * NBK + g] = s[tid] - v;     // exclusive within bin (no global base)
    if (tid == GB - 1) tot[g] = s[tid];
}

// ---- offscanB: scan of NBK bin totals -> offs256 ----
__launch_bounds__(NBK)
__global__ void offscanB_kernel(const int* __restrict__ tot, int* __restrict__ offs256) {
    __shared__ int s[NBK];
    const int t = threadIdx.x;
    int v = tot[t];
    s[t] = v;
    for (int off = 1; off < NBK; off <<= 1) {
        __syncthreads();
        int t2 = (t >= off) ? s[t - off] : 0;
        __syncthreads();
        s[t] += t2;
    }
    __syncthreads();
    offs256[t] = s[t] - v;
    if (t == NBK - 1) offs256[NBK] = s[t];
}

// ---- pass B: block counting sort, atomic-free coalesced run writes ----
__launch_bounds__(512)
__global__ void blocksort_kernel(const int* __restrict__ etype, const int* __restrict__ eidx,
                                 const int* __restrict__ boff, const int* __restrict__ offs256,
                                 uint32* __restrict__ binned, int E) {
    __shared__ uint32 raw[SCH];
    __shared__ uint32 srt[SCH];
    __shared__ int lhist[NBK];
    __shared__ int loff[NBK + 1];
    __shared__ int lcur[NBK];
    __shared__ int bbase[NBK];
    __shared__ int sc[NBK];
    const int tid  = threadIdx.x;
    const int wv   = tid >> 6;
    const int lane = tid & 63;

    if (tid < NBK) bbase[tid] = boff[blockIdx.x * NBK + tid] + offs256[tid];
    int per = (E + GB - 1) / GB;
    int ebeg = blockIdx.x * per;
    int eend = min(E, ebeg + per);

    for (int cb = ebeg; cb < eend; cb += SCH / 2) {
        const int ne = min(SCH / 2, eend - cb);
        const int m  = 2 * ne;
        if (tid < NBK) lhist[tid] = 0;
        __syncthreads();
        for (int i = tid; i < ne; i += 512) {
            int e  = cb + i;
            int r  = etype[e];
            int sS = eidx[e];
            int sD = eidx[E + e];
            int ch = r >> 5;
            int rb = (r & 31) << 1;
            raw[2 * i]     = ((uint32)ch << 24) | ((uint32)rb << 16) | (uint32)sS;
            raw[2 * i + 1] = ((uint32)ch << 24) | ((uint32)(rb + 1) << 16) | (uint32)sD;
            atomicAdd(&lhist[(ch << 3) | (sS >> 13)], 1);
            atomicAdd(&lhist[(ch << 3) | (sD >> 13)], 1);
        }
        __syncthreads();
        if (tid < NBK) sc[tid] = lhist[tid];
        for (int off = 1; off < NBK; off <<= 1) {
            __syncthreads();
            int t2 = (tid < NBK && tid >= off) ? sc[tid - off] : 0;
            __syncthreads();
            if (tid < NBK) sc[tid] += t2;
        }
        __syncthreads();
        if (tid < NBK) {
            loff[tid] = sc[tid] - lhist[tid];
            lcur[tid] = loff[tid];
            if (tid == NBK - 1) loff[NBK] = sc[tid];
        }
        __syncthreads();
        for (int i = tid; i < m; i += 512) {
            uint32 pk = raw[i];
            int k = (int)((pk >> 24) << 3) | (int)((pk & 0xFFFFu) >> 13);
            int pos = atomicAdd(&lcur[k], 1);
            srt[pos] = pk;
        }
        __syncthreads();
        for (int b = wv; b < NBK; b += 8) {
            int lo = loff[b];
            int c  = loff[b + 1] - lo;
            if (c > 0) {
                int dst = bbase[b];
                for (int i = lane; i < c; i += 64) binned[dst + i] = srt[lo + i];
                if (lane == 0) bbase[b] = dst + c;
            }
        }
        __syncthreads();
    }
}

// ---- sortbucket: per bucket, 64-bin LDS counting sort -> coalesced list ----
__launch_bounds__(512)
__global__ void sortbucket_kernel(const uint32* __restrict__ binned,
                                  const int* __restrict__ offs256,
                                  uint16* __restrict__ list, int* __restrict__ offs16k,
                                  int total) {
    __shared__ uint16 sorted[SCAP];
    __shared__ int hist[64];
    __shared__ int cur[64];
    __shared__ int scn[65];
    __shared__ int sc[64];
    const int bk  = blockIdx.x;
    const int tid = threadIdx.x;
    const int beg = offs256[bk];
    const int end = offs256[bk + 1];
    const int len = end - beg;

    if (tid < 64) hist[tid] = 0;
    __syncthreads();
    for (int i = tid; i < len; i += 512)
        atomicAdd(&hist[(binned[beg + i] >> 16) & 63], 1);
    __syncthreads();
    if (tid < 64) sc[tid] = hist[tid];
    for (int off = 1; off < 64; off <<= 1) {
        __syncthreads();
        int t2 = (tid < 64 && tid >= off) ? sc[tid - off] : 0;
        __syncthreads();
        if (tid < 64) sc[tid] += t2;
    }
    __syncthreads();
    if (tid < 64) {
        scn[tid] = sc[tid] - hist[tid];
        cur[tid] = scn[tid];
        if (tid == 63) scn[64] = sc[63];
    }
    __syncthreads();
    if (tid < 64) offs16k[bk * 64 + tid] = beg + scn[tid];
    if (bk == 0 && tid == 64) offs16k[NBK * 64] = total;

    if (len <= SCAP) {
        for (int i = tid; i < len; i += 512) {
            uint32 e = binned[beg + i];
            int p = atomicAdd(&cur[(e >> 16) & 63], 1);
            sorted[p] = (uint16)(e & 0xFFFF);
        }
        __syncthreads();
        for (int i = tid; i < len; i += 512) list[beg + i] = sorted[i];
    } else {
        for (int i = tid; i < len; i += 512) {
            uint32 e = binned[beg + i];
            int p = atomicAdd(&cur[(e >> 16) & 63], 1);
            list[beg + p] = (uint16)(e & 0xFFFF);
        }
    }
}

// -------- partial8: 512 thr = 16 streams/block, each stream owns a CONTIGUOUS
// ~m/16 entry range -> one ~8-deep latency batch per stream. fp16 __hadd2 payload.
// bid&7 = g pins the XCD-local cmp slice (unchanged). --------
__launch_bounds__(512)
__global__ void partial8_kernel(const uint16* __restrict__ list,
                                const uint32* __restrict__ cmp,
                                const int* __restrict__ offs16k,
                                uint16* __restrict__ partial) {
    const int g    = blockIdx.x & 7;
    const int rest = blockIdx.x >> 3;
    const int rsl  = rest & 63;
    const int ch   = rest >> 6;
    const int b16  = ((ch * 8 + g) << 6) | rsl;
    const int tid  = threadIdx.x;
    const int w    = tid >> 6;          // 0..7
    const int lane = tid & 63;
    const int sub  = lane / 25;         // 0,1 active; 2 idle
    const int w25  = lane % 25;
    const int laneOff = w25 * 4;
    const int stream = w * 2 + sub;     // 0..15 (valid when sub<2)

    __shared__ uint16 sl[CHUNK];
    __shared__ float  red[16][DD];

    const int beg = offs16k[b16];
    const int end = offs16k[b16 + 1];

    __half2 h0 = __floats2half2_rn(0.f, 0.f);
    __half2 h1 = h0, h2 = h0, h3 = h0;

    for (int base = beg; base < end; base += CHUNK) {
        const int m = min(CHUNK, end - base);
        for (int i = tid; i < m; i += 512) sl[i] = list[base + i];
        __syncthreads();
        if (sub < 2) {
            const int per = (m + 15) >> 4;
            int i  = stream * per;
            const int i1 = min(m, i + per);
            for (; i + 7 < i1; i += 8) {        // 8 independent gathers in flight
                int s0 = sl[i],     s1 = sl[i + 1], s2 = sl[i + 2], s3 = sl[i + 3];
                int s4 = sl[i + 4], s5 = sl[i + 5], s6 = sl[i + 6], s7 = sl[i + 7];
                uint4 v0 = *(const uint4*)(cmp + (size_t)s0 * 100 + laneOff);
                uint4 v1 = *(const uint4*)(cmp + (size_t)s1 * 100 + laneOff);
                uint4 v2 = *(const uint4*)(cmp + (size_t)s2 * 100 + laneOff);
                uint4 v3 = *(const uint4*)(cmp + (size_t)s3 * 100 + laneOff);
                uint4 v4 = *(const uint4*)(cmp + (size_t)s4 * 100 + laneOff);
                uint4 v5 = *(const uint4*)(cmp + (size_t)s5 * 100 + laneOff);
                uint4 v6 = *(const uint4*)(cmp + (size_t)s6 * 100 + laneOff);
                uint4 v7 = *(const uint4*)(cmp + (size_t)s7 * 100 + laneOff);
                h0 = __hadd2(h0, __hadd2(__hadd2(__hadd2(ash2(v0.x), ash2(v1.x)),
                                                 __hadd2(ash2(v2.x), ash2(v3.x))),
                                         __hadd2(__hadd2(ash2(v4.x), ash2(v5.x)),
                                                 __hadd2(ash2(v6.x), ash2(v7.x)))));
                h1 = __hadd2(h1, __hadd2(__hadd2(__hadd2(ash2(v0.y), ash2(v1.y)),
                                                 __hadd2(ash2(v2.y), ash2(v3.y))),
                                         __hadd2(__hadd2(ash2(v4.y), ash2(v5.y)),
                                                 __hadd2(ash2(v6.y), ash2(v7.y)))));
                h2 = __hadd2(h2, __hadd2(__hadd2(__hadd2(ash2(v0.z), ash2(v1.z)),
                                                 __hadd2(ash2(v2.z), ash2(v3.z))),
                                         __hadd2(__hadd2(ash2(v4.z), ash2(v5.z)),
                                                 __hadd2(ash2(v6.z), ash2(v7.z)))));
                h3 = __hadd2(h3, __hadd2(__hadd2(__hadd2(ash2(v0.w), ash2(v1.w)),
                                                 __hadd2(ash2(v2.w), ash2(v3.w))),
                                         __hadd2(__hadd2(ash2(v4.w), ash2(v5.w)),
                                                 __hadd2(ash2(v6.w), ash2(v7.w)))));
            }
            for (; i < i1; ++i) {
                int s0 = sl[i];
                uint4 v0 = *(const uint4*)(cmp + (size_t)s0 * 100 + laneOff);
                h0 = __hadd2(h0, ash2(v0.x));
                h1 = __hadd2(h1, ash2(v0.y));
                h2 = __hadd2(h2, ash2(v0.z));
                h3 = __hadd2(h3, ash2(v0.w));
            }
        }
        __syncthreads();
    }

    if (sub < 2) {
        int c = w25 * 8;
        red[stream][c]     = __low2float(h0);  red[stream][c + 1] = __high2float(h0);
        red[stream][c + 2] = __low2float(h1);  red[stream][c + 3] = __high2float(h1);
        red[stream][c + 4] = __low2float(h2);  red[stream][c + 5] = __high2float(h2);
        red[stream][c + 6] = __low2float(h3);  red[stream][c + 7] = __high2float(h3);
    }
    __syncthreads();

    if (tid < DD) {
        float s = 0.f;
        #pragma unroll
        for (int q = 0; q < 16; ++q) s += red[q][tid];
        partial[(size_t)b16 * DD + tid] = f2bf(s);
    }
}

// ---- prep2: build bf16 operands Xb/Hb (MP x KP) and Wib/Whb (NP x KP) ----
__global__ void prep2_kernel(const uint16* __restrict__ partial,
                             const int* __restrict__ offs16k,
                             const float* __restrict__ dyn,
                             const float* __restrict__ W_ih, const float* __restrict__ W_hh,
                             uint32* __restrict__ Xb, uint32* __restrict__ Hb,
                             uint32* __restrict__ Wib, uint32* __restrict__ Whb, int RS2) {
    const int KU = KP / 2;
    int idx = blockIdx.x * blockDim.x + threadIdx.x;
    int XU = MP * KU, WU = NP * KU;
    const uint32* pp = (const uint32*)partial;
    if (idx < XU) {
        int row = idx / KU, kk = (idx - row * KU) * 2;
        uint32 o = 0;
        if (row < RS2 && kk < DD) {
            int ch = row >> 6, rsl = row & 63;
            float s0 = 0.f, s1 = 0.f;
            int n = 0;
            #pragma unroll
            for (int g = 0; g < 8; ++g) {
                int b16 = ((ch * 8 + g) << 6) | rsl;
                n += offs16k[b16 + 1] - offs16k[b16];
                uint32 v = pp[b16 * 100 + (kk >> 1)];
                s0 += asf(v << 16);
                s1 += asf(v & 0xFFFF0000u);
            }
            float rc = (n > 0) ? 1.f / (float)n : 0.f;
            o = packbf(s0 * rc, s1 * rc);
        }
        Xb[idx] = o;
    } else if (idx < 2 * XU) {
        int k2 = idx - XU;
        int row = k2 / KU, kk = (k2 - row * KU) * 2;
        uint32 o = 0;
        if (row < RS2 && kk < DD) {
            int r = row >> 1, side = row & 1;
            float h0 = dyn[((size_t)r * DD + kk) * 2 + side];
            float h1 = dyn[((size_t)r * DD + kk + 1) * 2 + side];
            o = packbf(h0, h1);
        }
        Hb[k2] = o;
    } else if (idx < 2 * XU + 2 * WU) {
        int k2 = idx - 2 * XU;
        const float* W = (k2 < WU) ? W_ih : W_hh;
        uint32* dst = (k2 < WU) ? Wib : Whb;
        if (k2 >= WU) k2 -= WU;
        int row = k2 / KU, kk = (k2 - row * KU) * 2;
        uint32 o = 0;
        if (row < DD3 && kk < DD) {
            o = packbf(W[(size_t)row * DD + kk], W[(size_t)row * DD + kk + 1]);
        }
        dst[k2] = o;
    }
}

// ---- mfma_gates: G[z] = A[z] @ B[z]^T via mfma_f32_16x16x32_bf16, 64x64 tiles ----
__launch_bounds__(256)
__global__ void mfma_gates_kernel(const uint32* __restrict__ Xb, const uint32* __restrict__ Hb,
                                  const uint32* __restrict__ Wib, const uint32* __restrict__ Whb,
                                  float* __restrict__ G) {
    __shared__ short As[64 * KP];
    __shared__ short Bs[64 * KP];
    const int nt  = blockIdx.x;
    const int mt  = blockIdx.y;
    const int z   = blockIdx.z;
    const int tid = threadIdx.x;

    const uint32* Asrc = (z ? Hb : Xb) + (size_t)mt * 64 * (KP / 2);
    const uint32* Bsrc = (z ? Whb : Wib) + (size_t)nt * 64 * (KP / 2);
    {
        const uint4* a4 = (const uint4*)Asrc;
        const uint4* b4 = (const uint4*)Bsrc;
        uint4* la = (uint4*)As;
        uint4* lb = (uint4*)Bs;
        const int n16 = 64 * KP * 2 / 16;
        for (int i = tid; i < n16; i += 256) { la[i] = a4[i]; lb[i] = b4[i]; }
    }
    __syncthreads();

    const int w    = tid >> 6;
    const int lane = tid & 63;
    const int qm   = (w & 1) * 32;
    const int qn   = (w >> 1) * 32;
    const int lr   = lane & 15;
    const int lk   = (lane >> 4) * 8;

    f32x4 acc00 = {0.f, 0.f, 0.f, 0.f}, acc01 = acc00, acc10 = acc00, acc11 = acc00;
    #pragma unroll
    for (int ks = 0; ks < 7; ++ks) {
        int kof = ks * 32 + lk;
        bf16x8 a0 = *(const bf16x8*)&As[(qm + lr) * KP + kof];
        bf16x8 a1 = *(const bf16x8*)&As[(qm + 16 + lr) * KP + kof];
        bf16x8 b0 = *(const bf16x8*)&Bs[(qn + lr) * KP + kof];
        bf16x8 b1 = *(const bf16x8*)&Bs[(qn + 16 + lr) * KP + kof];
        acc00 = __builtin_amdgcn_mfma_f32_16x16x32_bf16(a0, b0, acc00, 0, 0, 0);
        acc01 = __builtin_amdgcn_mfma_f32_16x16x32_bf16(a0, b1, acc01, 0, 0, 0);
        acc10 = __builtin_amdgcn_mfma_f32_16x16x32_bf16(a1, b0, acc10, 0, 0, 0);
        acc11 = __builtin_amdgcn_mfma_f32_16x16x32_bf16(a1, b1, acc11, 0, 0, 0);
    }

    float* Gz = G + (size_t)z * MP * NP;
    const int mb = mt * 64 + qm + (lane >> 4) * 4;
    const int nb = nt * 64 + qn + lr;
    #pragma unroll
    for (int r = 0; r < 4; ++r) {
        Gz[(size_t)(mb + r) * NP + nb]           = acc00[r];
        Gz[(size_t)(mb + r) * NP + nb + 16]      = acc01[r];
        Gz[(size_t)(mb + 16 + r) * NP + nb]      = acc10[r];
        Gz[(size_t)(mb + 16 + r) * NP + nb + 16] = acc11[r];
    }
}

// ---- gruf2: elementwise GRU combine (adds biases here) ----
__global__ void gruf2_kernel(const float* __restrict__ G, const float* __restrict__ dyn,
                             const float* __restrict__ b_ih, const float* __restrict__ b_hh,
                             float* __restrict__ out, int RS2) {
    int idx = blockIdx.x * blockDim.x + threadIdx.x;
    int total = RS2 * DD;
    if (idx >= total) return;
    int rs = idx / DD, t = idx - rs * DD;
    int r = rs >> 1, side = rs & 1;
    const float* Gi = G;
    const float* Gh = G + (size_t)MP * NP;
    size_t base = (size_t)rs * NP;
    float ga   = Gi[base + t]          + b_ih[t]          + Gh[base + t]          + b_hh[t];
    float gz   = Gi[base + DD + t]     + b_ih[DD + t]     + Gh[base + DD + t]     + b_hh[DD + t];
    float gi_n = Gi[base + 2 * DD + t] + b_ih[2 * DD + t];
    float gh_n = Gh[base + 2 * DD + t] + b_hh[2 * DD + t];
    float rg = 1.f / (1.f + __expf(-ga));
    float zz = 1.f / (1.f + __expf(-gz));
    float nn = tanhf(gi_n + rg * gh_n);
    float h  = dyn[((size_t)r * DD + t) * 2 + side];
    out[((size_t)r * DD + t) * 2 + side] = (1.f - zz) * nn + zz * h;
}

// ================= fallback path (tiny ws): atomics into d_out ================
__global__ void hist_kernel(const int* __restrict__ etype, int* __restrict__ cnt,
                            int E, int R) {
    __shared__ int lc[1024];
    for (int i = threadIdx.x; i < R; i += blockDim.x) lc[i] = 0;
    __syncthreads();
    int stride = gridDim.x * blockDim.x;
    for (int i = blockIdx.x * blockDim.x + threadIdx.x; i < E; i += stride)
        atomicAdd(&lc[etype[i]], 1);
    __syncthreads();
    for (int i = threadIdx.x; i < R; i += blockDim.x)
        if (lc[i]) atomicAdd(&cnt[i], lc[i]);
}

__global__ void atomic_acc_kernel(const int* __restrict__ eidx, const int* __restrict__ etype,
                                  const int* __restrict__ node_id, const float* __restrict__ emb,
                                  float* __restrict__ acc, int E) {
    int gtid = blockIdx.x * blockDim.x + threadIdx.x;
    int wave = gtid >> 6, lane = gtid & 63;
    int nwaves = (gridDim.x * blockDim.x) >> 6;
    for (int e = wave; e < E; e += nwaves) {
        int r = etype[e];
        float* dst = acc + (size_t)r * DD * 2;
        for (int side = 0; side < 2; ++side) {
            int nid = node_id[eidx[(size_t)side * E + e]];
            const float* row = emb + (size_t)nid * DD;
            for (int d = lane; d < DD; d += 64)
                atomicAdd(&dst[d * 2 + side], row[d]);
        }
    }
}

__launch_bounds__(256)
__global__ void gru_inplace_kernel(const float* __restrict__ dyn, const float* __restrict__ W_ih,
                                   const float* __restrict__ W_hh, const float* __restrict__ b_ih,
                                   const float* __restrict__ b_hh, const int* __restrict__ cnt,
                                   float* __restrict__ out) {
    const int r = blockIdx.x, side = blockIdx.y, tid = threadIdx.x;
    __shared__ float xs[DD], hs[DD], gi[DD3], gh[DD3];
    if (tid < DD) {
        float s = out[((size_t)r * DD + tid) * 2 + side];
        int n = cnt[r];
        xs[tid] = (n > 0) ? s / (float)n : 0.f;
        hs[tid] = dyn[((size_t)r * DD + tid) * 2 + side];
    }
    __syncthreads();
    for (int jj = tid; jj < DD3; jj += 256) {
        float a = b_ih[jj], c = b_hh[jj];
        const float* rI = W_ih + (size_t)jj * DD;
        const float* rH = W_hh + (size_t)jj * DD;
        for (int k = 0; k < DD; ++k) { a = fmaf(xs[k], rI[k], a); c = fmaf(hs[k], rH[k], c); }
        gi[jj] = a; gh[jj] = c;
    }
    __syncthreads();
    if (tid < DD) {
        float rr = 1.f / (1.f + __expf(-(gi[tid] + gh[tid])));
        float zz = 1.f / (1.f + __expf(-(gi[DD + tid] + gh[DD + tid])));
        float nn = tanhf(gi[2 * DD + tid] + rr * gh[2 * DD + tid]);
        out[((size_t)r * DD + tid) * 2 + side] = (1.f - zz) * nn + zz * hs[tid];
    }
}

extern "C" void kernel_launch(void* const* d_in, const int* in_sizes, int n_in,
                              void* d_out, int out_size, void* d_ws, size_t ws_size,
                              hipStream_t stream) {
    const int*   eidx    = (const int*)d_in[0];
    const int*   etype   = (const int*)d_in[1];
    const int*   node_id = (const int*)d_in[2];
    const float* emb     = (const float*)d_in[3];
    const float* dyn     = (const float*)d_in[4];
    const float* W_ih    = (const float*)d_in[5];
    const float* W_hh    = (const float*)d_in[6];
    const float* b_ih    = (const float*)d_in[7];
    const float* b_hh    = (const float*)d_in[8];
    float*       out     = (float*)d_out;

    const int E   = in_sizes[1];
    const int NB  = in_sizes[2];               // 50,000
    const int D   = in_sizes[7] / 3;           // 200
    const int R   = in_sizes[4] / (2 * D);     // 1000
    const int RS2 = R * 2;                     // 2000

    char* p = (char*)d_ws;
    auto take = [&](size_t bytes) { char* q = p; p += (bytes + 255) & ~(size_t)255; return q; };
    int*    boff    = (int*)   take((size_t)GB * NBK * 4);        // 256 KB
    int*    tot     = (int*)   take((size_t)NBK * 4);
    int*    offs256 = (int*)   take((size_t)(NBK + 1) * 4);
    int*    offs16k = (int*)   take((size_t)(NBK * 64 + 1) * 4);
    uint32* cmp     = (uint32*)take((size_t)NB * 100 * 4);        // 20 MB
    uint16* list    = (uint16*)take((size_t)2 * E * 2);           // 4 MB
    uint16* partial = (uint16*)take((size_t)NBK * 64 * DD * 2);   // 6.55 MB
    uint32* binned2 = (uint32*)take((size_t)2 * E * 4);           // 8 MB (own region)
    size_t need_full = (size_t)(p - (char*)d_ws);

    float*  G      = (float*)cmp;            // cmp dead after partial8
    const int KU = KP / 2;
    uint32* Xb  = (uint32*)list;             // list dead after partial8
    uint32* Hb  = Xb + (size_t)MP * KU;
    uint32* Wib = Hb + (size_t)MP * KU;
    uint32* Whb = Wib + (size_t)NP * KU;
    size_t ovl_list = (size_t)(2 * MP + 2 * NP) * KU * 4;
    size_t ovl_cmp2 = (size_t)2 * MP * NP * 4;
    const bool overlay_ok = (ovl_list <= (size_t)2 * E * 2) &&
                            (ovl_cmp2 <= (size_t)NB * 100 * 4);

    const bool fits = (ws_size >= need_full) && (NB <= 50000) && (R == 1000) &&
                      (D == 200) && overlay_ok && (E <= 1000000);
    if (fits) {
        hist_compact_kernel<<<GB + 768, 512, 0, stream>>>(etype, eidx, boff, E,
                                                          node_id, emb, cmp, NB);
        offscanA_kernel<<<NBK, GB, 0, stream>>>(boff, tot);
        offscanB_kernel<<<1, NBK, 0, stream>>>(tot, offs256);
        blocksort_kernel<<<GB, 512, 0, stream>>>(etype, eidx, boff, offs256, binned2, E);
        sortbucket_kernel<<<NBK, 512, 0, stream>>>(binned2, offs256, list, offs16k, 2 * E);
        partial8_kernel<<<NBK * 64, 512, 0, stream>>>(list, cmp, offs16k, partial);
        int ptot = 2 * MP * KU + 2 * NP * KU;
        prep2_kernel<<<(ptot + 255) / 256, 256, 0, stream>>>(partial, offs16k, dyn, W_ih, W_hh,
                                                             Xb, Hb, Wib, Whb, RS2);
        dim3 mg(NP / 64, MP / 64, 2);
        mfma_gates_kernel<<<mg, 256, 0, stream>>>(Xb, Hb, Wib, Whb, G);
        gruf2_kernel<<<(RS2 * DD + 255) / 256, 256, 0, stream>>>(G, dyn, b_ih, b_hh, out, RS2);
    } else {
        int* cnt = (int*)d_ws;
        zero_kernel<<<32, 256, 0, stream>>>(cnt, R);
        hist_kernel<<<512, 256, 0, stream>>>(etype, cnt, E, R);
        zerof_kernel<<<(R * D * 2 + 255) / 256, 256, 0, stream>>>(out, R * D * 2);
        atomic_acc_kernel<<<2048, 256, 0, stream>>>(eidx, etype, node_id, emb, out, E);
        dim3 grid(R, 2);
        gru_inplace_kernel<<<grid, 256, 0, stream>>>(dyn, W_ih, W_hh, b_ih, b_hh, cnt, out);
    }
}

// Round 22
// 116.917 us; speedup vs baseline: 1.1246x; 1.1246x over previous
//
#include <hip/hip_runtime.h>
#include <hip/hip_fp16.h>
#include <math.h>

// Problem constants: E=1,000,000  R=1000  D=200  N_BATCH=50,000  N_TOTAL=100,000
#define DD     200
#define DD3    600
#define NBK    256     // radix buckets = chunk(r>>5, 32) * 8 + g(slot>>13, 8)
#define GB     256     // sort grid blocks (one per CU)
#define SCH    8192    // blocksort entries per chunk (4096 edges)
#define SCAP   11264   // sortbucket LDS capacity (uint16)
#define CHUNK  1024    // partial7 slot-staging chunk
#define KP     232     // padded K (bf16): 464B row stride (16B-aligned b128 reads)
#define MP     2048    // padded M (rs rows)
#define NP     640     // padded N (gate cols)

typedef unsigned int   uint32;
typedef unsigned short uint16;
typedef __attribute__((ext_vector_type(8))) short bf16x8;
typedef __attribute__((ext_vector_type(4))) float f32x4;

static __device__ inline float bf2f(uint16 u) {
    union { uint32 i; float f; } x; x.i = ((uint32)u) << 16; return x.f;
}
static __device__ inline uint16 f2bf(float f) {
    union { float f; uint32 i; } x; x.f = f;
    return (uint16)((x.i + 0x7FFFu + ((x.i >> 16) & 1u)) >> 16);
}
static __device__ inline float asf(uint32 u) {
    union { uint32 i; float f; } x; x.i = u; return x.f;
}
static __device__ inline uint32 packbf(float a, float b) {
    return (uint32)f2bf(a) | ((uint32)f2bf(b) << 16);
}
static __device__ inline uint32 packh2(float a, float b) {
    __half2 h = __floats2half2_rn(a, b);
    union { __half2 h; uint32 u; } x; x.h = h; return x.u;
}
static __device__ inline __half2 ash2(uint32 u) {
    union { uint32 u; __half2 h; } x; x.u = u; return x.h;
}

// ---------------- zero int counters ----------------
__global__ void zero_kernel(int* __restrict__ cnt, int n) {
    int stride = gridDim.x * blockDim.x;
    for (int i = blockIdx.x * blockDim.x + threadIdx.x; i < n; i += stride) cnt[i] = 0;
}

// ---------------- zero float buffer ----------------
__global__ void zerof_kernel(float* __restrict__ p, int n) {
    int stride = gridDim.x * blockDim.x;
    for (int i = blockIdx.x * blockDim.x + threadIdx.x; i < n; i += stride) p[i] = 0.f;
}

// ---- fused pass A: blocks 0..GB-1 histogram -> boff[blk][bin];
//      blocks GB..  compact rows to fp16 (independent work, overlapped) ----
__launch_bounds__(512)
__global__ void hist_compact_kernel(const int* __restrict__ etype, const int* __restrict__ eidx,
                                    int* __restrict__ boff, int E,
                                    const int* __restrict__ node_id, const float* __restrict__ emb,
                                    uint32* __restrict__ cmp, int NB) {
    const int tid = threadIdx.x;
    if (blockIdx.x < GB) {
        __shared__ int lc[NBK];
        if (tid < NBK) lc[tid] = 0;
        __syncthreads();
        int per = (E + GB - 1) / GB;
        int beg = blockIdx.x * per;
        int end = min(E, beg + per);
        for (int e = beg + tid; e < end; e += 512) {
            int r  = etype[e];
            int ch = r >> 5;
            atomicAdd(&lc[(ch << 3) | (eidx[e] >> 13)], 1);
            atomicAdd(&lc[(ch << 3) | (eidx[E + e] >> 13)], 1);
        }
        __syncthreads();
        if (tid < NBK) boff[blockIdx.x * NBK + tid] = lc[tid];
    } else {
        int idx = (blockIdx.x - GB) * 512 + tid;
        int stride = (gridDim.x - GB) * 512;
        int total = NB * 50;
        for (; idx < total; idx += stride) {
            int s = idx / 50, q = idx - s * 50;
            int nid = node_id[s];
            float4 v = *(const float4*)(emb + (size_t)nid * DD + 4 * q);
            *(uint2*)(cmp + (size_t)s * 100 + 2 * q) = make_uint2(packh2(v.x, v.y), packh2(v.z, v.w));
        }
    }
}

// ---- offscanA: per-bin parallel scan over GB block-counts (grid NBK, GB thr) ----
__launch_bounds__(GB)
__global__ void offscanA_kernel(int* __restrict__ boff, int* __restrict__ tot) {
    __shared__ int s[GB];
    const int g   = blockIdx.x;       // bin
    const int tid = threadIdx.x;      // block index
    int v = boff[(size_t)tid * NBK + g];
    s[tid] = v;
    for (int off = 1; off < GB; off <<= 1) {
        __syncthreads();
        int t2 = (tid >= off) ? s[tid - off] : 0;
        __syncthreads();
        s[tid] += t2;
    }
    __syncthreads();
    boff[(size_t)tid * NBK + g] = s[tid] - v;     // exclusive within bin (no global base)
    if (tid == GB - 1) tot[g] = s[tid];
}

// ---- offscanB: scan of NBK bin totals -> offs256 ----
__launch_bounds__(NBK)
__global__ void offscanB_kernel(const int* __restrict__ tot, int* __restrict__ offs256) {
    __shared__ int s[NBK];
    const int t = threadIdx.x;
    int v = tot[t];
    s[t] = v;
    for (int off = 1; off < NBK; off <<= 1) {
        __syncthreads();
        int t2 = (t >= off) ? s[t - off] : 0;
        __syncthreads();
        s[t] += t2;
    }
    __syncthreads();
    offs256[t] = s[t] - v;
    if (t == NBK - 1) offs256[NBK] = s[t];
}

// ---- pass B: block counting sort, atomic-free coalesced run writes ----
__launch_bounds__(512)
__global__ void blocksort_kernel(const int* __restrict__ etype, const int* __restrict__ eidx,
                                 const int* __restrict__ boff, const int* __restrict__ offs256,
                                 uint32* __restrict__ binned, int E) {
    __shared__ uint32 raw[SCH];
    __shared__ uint32 srt[SCH];
    __shared__ int lhist[NBK];
    __shared__ int loff[NBK + 1];
    __shared__ int lcur[NBK];
    __shared__ int bbase[NBK];
    __shared__ int sc[NBK];
    const int tid  = threadIdx.x;
    const int wv   = tid >> 6;
    const int lane = tid & 63;

    if (tid < NBK) bbase[tid] = boff[blockIdx.x * NBK + tid] + offs256[tid];
    int per = (E + GB - 1) / GB;
    int ebeg = blockIdx.x * per;
    int eend = min(E, ebeg + per);

    for (int cb = ebeg; cb < eend; cb += SCH / 2) {
        const int ne = min(SCH / 2, eend - cb);
        const int m  = 2 * ne;
        if (tid < NBK) lhist[tid] = 0;
        __syncthreads();
        for (int i = tid; i < ne; i += 512) {
            int e  = cb + i;
            int r  = etype[e];
            int sS = eidx[e];
            int sD = eidx[E + e];
            int ch = r >> 5;
            int rb = (r & 31) << 1;
            raw[2 * i]     = ((uint32)ch << 24) | ((uint32)rb << 16) | (uint32)sS;
            raw[2 * i + 1] = ((uint32)ch << 24) | ((uint32)(rb + 1) << 16) | (uint32)sD;
            atomicAdd(&lhist[(ch << 3) | (sS >> 13)], 1);
            atomicAdd(&lhist[(ch << 3) | (sD >> 13)], 1);
        }
        __syncthreads();
        if (tid < NBK) sc[tid] = lhist[tid];
        for (int off = 1; off < NBK; off <<= 1) {
            __syncthreads();
            int t2 = (tid < NBK && tid >= off) ? sc[tid - off] : 0;
            __syncthreads();
            if (tid < NBK) sc[tid] += t2;
        }
        __syncthreads();
        if (tid < NBK) {
            loff[tid] = sc[tid] - lhist[tid];
            lcur[tid] = loff[tid];
            if (tid == NBK - 1) loff[NBK] = sc[tid];
        }
        __syncthreads();
        for (int i = tid; i < m; i += 512) {
            uint32 pk = raw[i];
            int k = (int)((pk >> 24) << 3) | (int)((pk & 0xFFFFu) >> 13);
            int pos = atomicAdd(&lcur[k], 1);
            srt[pos] = pk;
        }
        __syncthreads();
        for (int b = wv; b < NBK; b += 8) {
            int lo = loff[b];
            int c  = loff[b + 1] - lo;
            if (c > 0) {
                int dst = bbase[b];
                for (int i = lane; i < c; i += 64) binned[dst + i] = srt[lo + i];
                if (lane == 0) bbase[b] = dst + c;
            }
        }
        __syncthreads();
    }
}

// ---- sortbucket: per bucket, 64-bin LDS counting sort -> coalesced list ----
__launch_bounds__(512)
__global__ void sortbucket_kernel(const uint32* __restrict__ binned,
                                  const int* __restrict__ offs256,
                                  uint16* __restrict__ list, int* __restrict__ offs16k,
                                  int total) {
    __shared__ uint16 sorted[SCAP];
    __shared__ int hist[64];
    __shared__ int cur[64];
    __shared__ int scn[65];
    __shared__ int sc[64];
    const int bk  = blockIdx.x;
    const int tid = threadIdx.x;
    const int beg = offs256[bk];
    const int end = offs256[bk + 1];
    const int len = end - beg;

    if (tid < 64) hist[tid] = 0;
    __syncthreads();
    for (int i = tid; i < len; i += 512)
        atomicAdd(&hist[(binned[beg + i] >> 16) & 63], 1);
    __syncthreads();
    if (tid < 64) sc[tid] = hist[tid];
    for (int off = 1; off < 64; off <<= 1) {
        __syncthreads();
        int t2 = (tid < 64 && tid >= off) ? sc[tid - off] : 0;
        __syncthreads();
        if (tid < 64) sc[tid] += t2;
    }
    __syncthreads();
    if (tid < 64) {
        scn[tid] = sc[tid] - hist[tid];
        cur[tid] = scn[tid];
        if (tid == 63) scn[64] = sc[63];
    }
    __syncthreads();
    if (tid < 64) offs16k[bk * 64 + tid] = beg + scn[tid];
    if (bk == 0 && tid == 64) offs16k[NBK * 64] = total;

    if (len <= SCAP) {
        for (int i = tid; i < len; i += 512) {
            uint32 e = binned[beg + i];
            int p = atomicAdd(&cur[(e >> 16) & 63], 1);
            sorted[p] = (uint16)(e & 0xFFFF);
        }
        __syncthreads();
        for (int i = tid; i < len; i += 512) list[beg + i] = sorted[i];
    } else {
        for (int i = tid; i < len; i += 512) {
            uint32 e = binned[beg + i];
            int p = atomicAdd(&cur[(e >> 16) & 63], 1);
            list[beg + p] = (uint16)(e & 0xFFFF);
        }
    }
}

// -------- partial7 (round-20 proven): 256 thr = 8 streams; fp16 __hadd2 payload;
// 8-deep strided batches; bid&7 = g pins the XCD-local cmp slice --------
__launch_bounds__(256)
__global__ void partial7_kernel(const uint16* __restrict__ list,
                                const uint32* __restrict__ cmp,
                                const int* __restrict__ offs16k,
                                uint16* __restrict__ partial) {
    const int g    = blockIdx.x & 7;
    const int rest = blockIdx.x >> 3;
    const int rsl  = rest & 63;
    const int ch   = rest >> 6;
    const int b16  = ((ch * 8 + g) << 6) | rsl;
    const int tid  = threadIdx.x;
    const int w    = tid >> 6;
    const int lane = tid & 63;
    const int sub  = lane / 25;
    const int w25  = lane % 25;
    const int laneOff = w25 * 4;

    __shared__ uint16 sl[CHUNK];
    __shared__ float  red[8][DD];

    const int beg = offs16k[b16];
    const int end = offs16k[b16 + 1];

    __half2 h0 = __floats2half2_rn(0.f, 0.f);
    __half2 h1 = h0, h2 = h0, h3 = h0;

    for (int base = beg; base < end; base += CHUNK) {
        const int m = min(CHUNK, end - base);
        for (int i = tid; i < m; i += 256) sl[i] = list[base + i];
        __syncthreads();
        if (sub < 2) {
            int i = w * 2 + sub;
            // 8 independent gathers in flight
            for (; i + 56 < m; i += 64) {
                int s0 = sl[i],      s1 = sl[i + 8],  s2 = sl[i + 16], s3 = sl[i + 24];
                int s4 = sl[i + 32], s5 = sl[i + 40], s6 = sl[i + 48], s7 = sl[i + 56];
                uint4 v0 = *(const uint4*)(cmp + (size_t)s0 * 100 + laneOff);
                uint4 v1 = *(const uint4*)(cmp + (size_t)s1 * 100 + laneOff);
                uint4 v2 = *(const uint4*)(cmp + (size_t)s2 * 100 + laneOff);
                uint4 v3 = *(const uint4*)(cmp + (size_t)s3 * 100 + laneOff);
                uint4 v4 = *(const uint4*)(cmp + (size_t)s4 * 100 + laneOff);
                uint4 v5 = *(const uint4*)(cmp + (size_t)s5 * 100 + laneOff);
                uint4 v6 = *(const uint4*)(cmp + (size_t)s6 * 100 + laneOff);
                uint4 v7 = *(const uint4*)(cmp + (size_t)s7 * 100 + laneOff);
                h0 = __hadd2(h0, __hadd2(__hadd2(__hadd2(ash2(v0.x), ash2(v1.x)),
                                                 __hadd2(ash2(v2.x), ash2(v3.x))),
                                         __hadd2(__hadd2(ash2(v4.x), ash2(v5.x)),
                                                 __hadd2(ash2(v6.x), ash2(v7.x)))));
                h1 = __hadd2(h1, __hadd2(__hadd2(__hadd2(ash2(v0.y), ash2(v1.y)),
                                                 __hadd2(ash2(v2.y), ash2(v3.y))),
                                         __hadd2(__hadd2(ash2(v4.y), ash2(v5.y)),
                                                 __hadd2(ash2(v6.y), ash2(v7.y)))));
                h2 = __hadd2(h2, __hadd2(__hadd2(__hadd2(ash2(v0.z), ash2(v1.z)),
                                                 __hadd2(ash2(v2.z), ash2(v3.z))),
                                         __hadd2(__hadd2(ash2(v4.z), ash2(v5.z)),
                                                 __hadd2(ash2(v6.z), ash2(v7.z)))));
                h3 = __hadd2(h3, __hadd2(__hadd2(__hadd2(ash2(v0.w), ash2(v1.w)),
                                                 __hadd2(ash2(v2.w), ash2(v3.w))),
                                         __hadd2(__hadd2(ash2(v4.w), ash2(v5.w)),
                                                 __hadd2(ash2(v6.w), ash2(v7.w)))));
            }
            // 4-deep mid-tail
            if (i + 24 < m) {
                int s0 = sl[i], s1 = sl[i + 8], s2 = sl[i + 16], s3 = sl[i + 24];
                uint4 v0 = *(const uint4*)(cmp + (size_t)s0 * 100 + laneOff);
                uint4 v1 = *(const uint4*)(cmp + (size_t)s1 * 100 + laneOff);
                uint4 v2 = *(const uint4*)(cmp + (size_t)s2 * 100 + laneOff);
                uint4 v3 = *(const uint4*)(cmp + (size_t)s3 * 100 + laneOff);
                h0 = __hadd2(h0, __hadd2(__hadd2(ash2(v0.x), ash2(v1.x)),
                                         __hadd2(ash2(v2.x), ash2(v3.x))));
                h1 = __hadd2(h1, __hadd2(__hadd2(ash2(v0.y), ash2(v1.y)),
                                         __hadd2(ash2(v2.y), ash2(v3.y))));
                h2 = __hadd2(h2, __hadd2(__hadd2(ash2(v0.z), ash2(v1.z)),
                                         __hadd2(ash2(v2.z), ash2(v3.z))));
                h3 = __hadd2(h3, __hadd2(__hadd2(ash2(v0.w), ash2(v1.w)),
                                         __hadd2(ash2(v2.w), ash2(v3.w))));
                i += 32;
            }
            for (; i < m; i += 8) {
                int s0 = sl[i];
                uint4 v0 = *(const uint4*)(cmp + (size_t)s0 * 100 + laneOff);
                h0 = __hadd2(h0, ash2(v0.x));
                h1 = __hadd2(h1, ash2(v0.y));
                h2 = __hadd2(h2, ash2(v0.z));
                h3 = __hadd2(h3, ash2(v0.w));
            }
        }
        __syncthreads();
    }

    if (sub < 2) {
        int row = w * 2 + sub;
        int c = w25 * 8;
        red[row][c]     = __low2float(h0);  red[row][c + 1] = __high2float(h0);
        red[row][c + 2] = __low2float(h1);  red[row][c + 3] = __high2float(h1);
        red[row][c + 4] = __low2float(h2);  red[row][c + 5] = __high2float(h2);
        red[row][c + 6] = __low2float(h3);  red[row][c + 7] = __high2float(h3);
    }
    __syncthreads();

    if (tid < DD) {
        float s = 0.f;
        #pragma unroll
        for (int q = 0; q < 8; ++q) s += red[q][tid];
        partial[(size_t)b16 * DD + tid] = f2bf(s);
    }
}

// ---- prep2: build bf16 operands Xb/Hb (MP x KP) and Wib/Whb (NP x KP) ----
__global__ void prep2_kernel(const uint16* __restrict__ partial,
                             const int* __restrict__ offs16k,
                             const float* __restrict__ dyn,
                             const float* __restrict__ W_ih, const float* __restrict__ W_hh,
                             uint32* __restrict__ Xb, uint32* __restrict__ Hb,
                             uint32* __restrict__ Wib, uint32* __restrict__ Whb, int RS2) {
    const int KU = KP / 2;
    int idx = blockIdx.x * blockDim.x + threadIdx.x;
    int XU = MP * KU, WU = NP * KU;
    const uint32* pp = (const uint32*)partial;
    if (idx < XU) {
        int row = idx / KU, kk = (idx - row * KU) * 2;
        uint32 o = 0;
        if (row < RS2 && kk < DD) {
            int ch = row >> 6, rsl = row & 63;
            float s0 = 0.f, s1 = 0.f;
            int n = 0;
            #pragma unroll
            for (int g = 0; g < 8; ++g) {
                int b16 = ((ch * 8 + g) << 6) | rsl;
                n += offs16k[b16 + 1] - offs16k[b16];
                uint32 v = pp[b16 * 100 + (kk >> 1)];
                s0 += asf(v << 16);
                s1 += asf(v & 0xFFFF0000u);
            }
            float rc = (n > 0) ? 1.f / (float)n : 0.f;
            o = packbf(s0 * rc, s1 * rc);
        }
        Xb[idx] = o;
    } else if (idx < 2 * XU) {
        int k2 = idx - XU;
        int row = k2 / KU, kk = (k2 - row * KU) * 2;
        uint32 o = 0;
        if (row < RS2 && kk < DD) {
            int r = row >> 1, side = row & 1;
            float h0 = dyn[((size_t)r * DD + kk) * 2 + side];
            float h1 = dyn[((size_t)r * DD + kk + 1) * 2 + side];
            o = packbf(h0, h1);
        }
        Hb[k2] = o;
    } else if (idx < 2 * XU + 2 * WU) {
        int k2 = idx - 2 * XU;
        const float* W = (k2 < WU) ? W_ih : W_hh;
        uint32* dst = (k2 < WU) ? Wib : Whb;
        if (k2 >= WU) k2 -= WU;
        int row = k2 / KU, kk = (k2 - row * KU) * 2;
        uint32 o = 0;
        if (row < DD3 && kk < DD) {
            o = packbf(W[(size_t)row * DD + kk], W[(size_t)row * DD + kk + 1]);
        }
        dst[k2] = o;
    }
}

// ---- mfma_gates: G[z] = A[z] @ B[z]^T via mfma_f32_16x16x32_bf16, 64x64 tiles ----
__launch_bounds__(256)
__global__ void mfma_gates_kernel(const uint32* __restrict__ Xb, const uint32* __restrict__ Hb,
                                  const uint32* __restrict__ Wib, const uint32* __restrict__ Whb,
                                  float* __restrict__ G) {
    __shared__ short As[64 * KP];
    __shared__ short Bs[64 * KP];
    const int nt  = blockIdx.x;
    const int mt  = blockIdx.y;
    const int z   = blockIdx.z;
    const int tid = threadIdx.x;

    const uint32* Asrc = (z ? Hb : Xb) + (size_t)mt * 64 * (KP / 2);
    const uint32* Bsrc = (z ? Whb : Wib) + (size_t)nt * 64 * (KP / 2);
    {
        const uint4* a4 = (const uint4*)Asrc;
        const uint4* b4 = (const uint4*)Bsrc;
        uint4* la = (uint4*)As;
        uint4* lb = (uint4*)Bs;
        const int n16 = 64 * KP * 2 / 16;
        for (int i = tid; i < n16; i += 256) { la[i] = a4[i]; lb[i] = b4[i]; }
    }
    __syncthreads();

    const int w    = tid >> 6;
    const int lane = tid & 63;
    const int qm   = (w & 1) * 32;
    const int qn   = (w >> 1) * 32;
    const int lr   = lane & 15;
    const int lk   = (lane >> 4) * 8;

    f32x4 acc00 = {0.f, 0.f, 0.f, 0.f}, acc01 = acc00, acc10 = acc00, acc11 = acc00;
    #pragma unroll
    for (int ks = 0; ks < 7; ++ks) {
        int kof = ks * 32 + lk;
        bf16x8 a0 = *(const bf16x8*)&As[(qm + lr) * KP + kof];
        bf16x8 a1 = *(const bf16x8*)&As[(qm + 16 + lr) * KP + kof];
        bf16x8 b0 = *(const bf16x8*)&Bs[(qn + lr) * KP + kof];
        bf16x8 b1 = *(const bf16x8*)&Bs[(qn + 16 + lr) * KP + kof];
        acc00 = __builtin_amdgcn_mfma_f32_16x16x32_bf16(a0, b0, acc00, 0, 0, 0);
        acc01 = __builtin_amdgcn_mfma_f32_16x16x32_bf16(a0, b1, acc01, 0, 0, 0);
        acc10 = __builtin_amdgcn_mfma_f32_16x16x32_bf16(a1, b0, acc10, 0, 0, 0);
        acc11 = __builtin_amdgcn_mfma_f32_16x16x32_bf16(a1, b1, acc11, 0, 0, 0);
    }

    float* Gz = G + (size_t)z * MP * NP;
    const int mb = mt * 64 + qm + (lane >> 4) * 4;
    const int nb = nt * 64 + qn + lr;
    #pragma unroll
    for (int r = 0; r < 4; ++r) {
        Gz[(size_t)(mb + r) * NP + nb]           = acc00[r];
        Gz[(size_t)(mb + r) * NP + nb + 16]      = acc01[r];
        Gz[(size_t)(mb + 16 + r) * NP + nb]      = acc10[r];
        Gz[(size_t)(mb + 16 + r) * NP + nb + 16] = acc11[r];
    }
}

// ---- gruf2: elementwise GRU combine (adds biases here) ----
__global__ void gruf2_kernel(const float* __restrict__ G, const float* __restrict__ dyn,
                             const float* __restrict__ b_ih, const float* __restrict__ b_hh,
                             float* __restrict__ out, int RS2) {
    int idx = blockIdx.x * blockDim.x + threadIdx.x;
    int total = RS2 * DD;
    if (idx >= total) return;
    int rs = idx / DD, t = idx - rs * DD;
    int r = rs >> 1, side = rs & 1;
    const float* Gi = G;
    const float* Gh = G + (size_t)MP * NP;
    size_t base = (size_t)rs * NP;
    float ga   = Gi[base + t]          + b_ih[t]          + Gh[base + t]          + b_hh[t];
    float gz   = Gi[base + DD + t]     + b_ih[DD + t]     + Gh[base + DD + t]     + b_hh[DD + t];
    float gi_n = Gi[base + 2 * DD + t] + b_ih[2 * DD + t];
    float gh_n = Gh[base + 2 * DD + t] + b_hh[2 * DD + t];
    float rg = 1.f / (1.f + __expf(-ga));
    float zz = 1.f / (1.f + __expf(-gz));
    float nn = tanhf(gi_n + rg * gh_n);
    float h  = dyn[((size_t)r * DD + t) * 2 + side];
    out[((size_t)r * DD + t) * 2 + side] = (1.f - zz) * nn + zz * h;
}

// ================= fallback path (tiny ws): atomics into d_out ================
__global__ void hist_kernel(const int* __restrict__ etype, int* __restrict__ cnt,
                            int E, int R) {
    __shared__ int lc[1024];
    for (int i = threadIdx.x; i < R; i += blockDim.x) lc[i] = 0;
    __syncthreads();
    int stride = gridDim.x * blockDim.x;
    for (int i = blockIdx.x * blockDim.x + threadIdx.x; i < E; i += stride)
        atomicAdd(&lc[etype[i]], 1);
    __syncthreads();
    for (int i = threadIdx.x; i < R; i += blockDim.x)
        if (lc[i]) atomicAdd(&cnt[i], lc[i]);
}

__global__ void atomic_acc_kernel(const int* __restrict__ eidx, const int* __restrict__ etype,
                                  const int* __restrict__ node_id, const float* __restrict__ emb,
                                  float* __restrict__ acc, int E) {
    int gtid = blockIdx.x * blockDim.x + threadIdx.x;
    int wave = gtid >> 6, lane = gtid & 63;
    int nwaves = (gridDim.x * blockDim.x) >> 6;
    for (int e = wave; e < E; e += nwaves) {
        int r = etype[e];
        float* dst = acc + (size_t)r * DD * 2;
        for (int side = 0; side < 2; ++side) {
            int nid = node_id[eidx[(size_t)side * E + e]];
            const float* row = emb + (size_t)nid * DD;
            for (int d = lane; d < DD; d += 64)
                atomicAdd(&dst[d * 2 + side], row[d]);
        }
    }
}

__launch_bounds__(256)
__global__ void gru_inplace_kernel(const float* __restrict__ dyn, const float* __restrict__ W_ih,
                                   const float* __restrict__ W_hh, const float* __restrict__ b_ih,
                                   const float* __restrict__ b_hh, const int* __restrict__ cnt,
                                   float* __restrict__ out) {
    const int r = blockIdx.x, side = blockIdx.y, tid = threadIdx.x;
    __shared__ float xs[DD], hs[DD], gi[DD3], gh[DD3];
    if (tid < DD) {
        float s = out[((size_t)r * DD + tid) * 2 + side];
        int n = cnt[r];
        xs[tid] = (n > 0) ? s / (float)n : 0.f;
        hs[tid] = dyn[((size_t)r * DD + tid) * 2 + side];
    }
    __syncthreads();
    for (int jj = tid; jj < DD3; jj += 256) {
        float a = b_ih[jj], c = b_hh[jj];
        const float* rI = W_ih + (size_t)jj * DD;
        const float* rH = W_hh + (size_t)jj * DD;
        for (int k = 0; k < DD; ++k) { a = fmaf(xs[k], rI[k], a); c = fmaf(hs[k], rH[k], c); }
        gi[jj] = a; gh[jj] = c;
    }
    __syncthreads();
    if (tid < DD) {
        float rr = 1.f / (1.f + __expf(-(gi[tid] + gh[tid])));
        float zz = 1.f / (1.f + __expf(-(gi[DD + tid] + gh[DD + tid])));
        float nn = tanhf(gi[2 * DD + tid] + rr * gh[2 * DD + tid]);
        out[((size_t)r * DD + tid) * 2 + side] = (1.f - zz) * nn + zz * hs[tid];
    }
}

extern "C" void kernel_launch(void* const* d_in, const int* in_sizes, int n_in,
                              void* d_out, int out_size, void* d_ws, size_t ws_size,
                              hipStream_t stream) {
    const int*   eidx    = (const int*)d_in[0];
    const int*   etype   = (const int*)d_in[1];
    const int*   node_id = (const int*)d_in[2];
    const float* emb     = (const float*)d_in[3];
    const float* dyn     = (const float*)d_in[4];
    const float* W_ih    = (const float*)d_in[5];
    const float* W_hh    = (const float*)d_in[6];
    const float* b_ih    = (const float*)d_in[7];
    const float* b_hh    = (const float*)d_in[8];
    float*       out     = (float*)d_out;

    const int E   = in_sizes[1];
    const int NB  = in_sizes[2];               // 50,000
    const int D   = in_sizes[7] / 3;           // 200
    const int R   = in_sizes[4] / (2 * D);     // 1000
    const int RS2 = R * 2;                     // 2000

    char* p = (char*)d_ws;
    auto take = [&](size_t bytes) { char* q = p; p += (bytes + 255) & ~(size_t)255; return q; };
    int*    boff    = (int*)   take((size_t)GB * NBK * 4);        // 256 KB
    int*    tot     = (int*)   take((size_t)NBK * 4);
    int*    offs256 = (int*)   take((size_t)(NBK + 1) * 4);
    int*    offs16k = (int*)   take((size_t)(NBK * 64 + 1) * 4);
    uint32* cmp     = (uint32*)take((size_t)NB * 100 * 4);        // 20 MB
    uint16* list    = (uint16*)take((size_t)2 * E * 2);           // 4 MB
    uint16* partial = (uint16*)take((size_t)NBK * 64 * DD * 2);   // 6.55 MB
    uint32* binned2 = (uint32*)take((size_t)2 * E * 4);           // 8 MB (own region)
    size_t need_full = (size_t)(p - (char*)d_ws);

    float*  G      = (float*)cmp;            // cmp dead after partial7
    const int KU = KP / 2;
    uint32* Xb  = (uint32*)list;             // list dead after partial7
    uint32* Hb  = Xb + (size_t)MP * KU;
    uint32* Wib = Hb + (size_t)MP * KU;
    uint32* Whb = Wib + (size_t)NP * KU;
    size_t ovl_list = (size_t)(2 * MP + 2 * NP) * KU * 4;
    size_t ovl_cmp2 = (size_t)2 * MP * NP * 4;
    const bool overlay_ok = (ovl_list <= (size_t)2 * E * 2) &&
                            (ovl_cmp2 <= (size_t)NB * 100 * 4);

    const bool fits = (ws_size >= need_full) && (NB <= 50000) && (R == 1000) &&
                      (D == 200) && overlay_ok && (E <= 1000000);
    if (fits) {
        hist_compact_kernel<<<GB + 768, 512, 0, stream>>>(etype, eidx, boff, E,
                                                          node_id, emb, cmp, NB);
        offscanA_kernel<<<NBK, GB, 0, stream>>>(boff, tot);
        offscanB_kernel<<<1, NBK, 0, stream>>>(tot, offs256);
        blocksort_kernel<<<GB, 512, 0, stream>>>(etype, eidx, boff, offs256, binned2, E);
        sortbucket_kernel<<<NBK, 512, 0, stream>>>(binned2, offs256, list, offs16k, 2 * E);
        partial7_kernel<<<NBK * 64, 256, 0, stream>>>(list, cmp, offs16k, partial);
        int ptot = 2 * MP * KU + 2 * NP * KU;
        prep2_kernel<<<(ptot + 255) / 256, 256, 0, stream>>>(partial, offs16k, dyn, W_ih, W_hh,
                                                             Xb, Hb, Wib, Whb, RS2);
        dim3 mg(NP / 64, MP / 64, 2);
        mfma_gates_kernel<<<mg, 256, 0, stream>>>(Xb, Hb, Wib, Whb, G);
        gruf2_kernel<<<(RS2 * DD + 255) / 256, 256, 0, stream>>>(G, dyn, b_ih, b_hh, out, RS2);
    } else {
        int* cnt = (int*)d_ws;
        zero_kernel<<<32, 256, 0, stream>>>(cnt, R);
        hist_kernel<<<512, 256, 0, stream>>>(etype, cnt, E, R);
        zerof_kernel<<<(R * D * 2 + 255) / 256, 256, 0, stream>>>(out, R * D * 2);
        atomic_acc_kernel<<<2048, 256, 0, stream>>>(eidx, etype, node_id, emb, out, E);
        dim3 grid(R, 2);
        gru_inplace_kernel<<<grid, 256, 0, stream>>>(dyn, W_ih, W_hh, b_ih, b_hh, cnt, out);
    }
}